// Round 1
// baseline (3220.045 us; speedup 1.0000x reference)
//
#include <hip/hip_runtime.h>

#define TT 1024
#define HH 128
#define G4 512

__device__ __forceinline__ float sigm(float x) {
    // 1/(1+e^-x); rcp is ~1ulp, saturates correctly at +-inf
    return __builtin_amdgcn_rcpf(1.0f + __expf(-x));
}
__device__ __forceinline__ float tanh_f(float x) {
    // 1 - 2/(1+e^{2x}); NaN-free saturation at both ends
    return 1.0f - 2.0f * __builtin_amdgcn_rcpf(1.0f + __expf(2.0f * x));
}

// ---------------- layer 0: input dim 1 (trivial input proj, fused) ----------
// grid 256 (one block per batch row), 512 threads (one per gate output).
// W_hh0 row lives in 128 VGPRs per thread; h,c live in LDS.
__global__ __launch_bounds__(512, 2) void lstm0(
    const float* __restrict__ x, const float* __restrict__ Wih,
    const float* __restrict__ Whh, const float* __restrict__ bih,
    const float* __restrict__ bhh, float* __restrict__ h0out)
{
    const int b = blockIdx.x;
    const int tid = threadIdx.x;
    __shared__ __align__(16) float hS[HH];
    __shared__ __align__(16) float cS[HH];
    __shared__ __align__(16) float gS[G4];

    float w[HH];
#pragma unroll
    for (int k = 0; k < HH; k += 4) {
        const float4 v = *reinterpret_cast<const float4*>(Whh + tid * HH + k);
        w[k] = v.x; w[k + 1] = v.y; w[k + 2] = v.z; w[k + 3] = v.w;
    }
    const float wih  = Wih[tid];
    const float bias = bih[tid] + bhh[tid];
    if (tid < HH) { hS[tid] = 0.0f; cS[tid] = 0.0f; }
    __syncthreads();

    const float* xb = x + b * TT;
    float* hb = h0out + (size_t)b * TT * HH;

    for (int t = 0; t < TT; ++t) {
        float a0 = fmaf(xb[t], wih, bias), a1 = 0.f, a2 = 0.f, a3 = 0.f;
#pragma unroll
        for (int k = 0; k < HH; k += 4) {
            const float4 hv = *reinterpret_cast<const float4*>(hS + k);  // broadcast
            a0 = fmaf(hv.x, w[k],     a0);
            a1 = fmaf(hv.y, w[k + 1], a1);
            a2 = fmaf(hv.z, w[k + 2], a2);
            a3 = fmaf(hv.w, w[k + 3], a3);
        }
        gS[tid] = (a0 + a1) + (a2 + a3);
        __syncthreads();
        if (tid < HH) {
            const float gi = sigm(gS[tid]);
            const float gf = sigm(gS[tid + HH]);
            const float gg = tanh_f(gS[tid + 2 * HH]);
            const float go = sigm(gS[tid + 3 * HH]);
            const float c = gf * cS[tid] + gi * gg;
            const float h = go * tanh_f(c);
            cS[tid] = c; hS[tid] = h;
            hb[t * HH + tid] = h;
        }
        __syncthreads();
    }
}

// ---------------- W_ih1 transpose: [512,128] -> [128,512] -------------------
__global__ void transp(const float* __restrict__ Wih1, float* __restrict__ WT)
{
    const int i = blockIdx.x * 256 + threadIdx.x;  // 0..65535
    const int j = i & (G4 - 1);
    const int k = i >> 9;
    WT[k * G4 + j] = Wih1[j * HH + k];
}

// ---------------- layer 1 + FC head -----------------------------------------
// Per 32-step chunk: stage h0 chunk in LDS, compute input projection xg
// (thread = 4 rows x 8 gate cols, W^T streamed coalesced from L2), stage xg in
// LDS, then run 32 sequential recurrent steps (W_hh1 row in VGPRs) with the FC
// dot fused on wave 0.
__global__ __launch_bounds__(512, 2) void lstm1(
    const float* __restrict__ h0in, const float* __restrict__ WT,
    const float* __restrict__ Whh, const float* __restrict__ bih,
    const float* __restrict__ bhh, const float* __restrict__ fcw,
    const float* __restrict__ fcb, float* __restrict__ out)
{
    const int b = blockIdx.x;
    const int tid = threadIdx.x;
    __shared__ __align__(16) float h0S[32][HH];   // 16 KB
    __shared__ __align__(16) float xgS[32][G4];   // 64 KB
    __shared__ __align__(16) float hS[HH];
    __shared__ __align__(16) float cS[HH];
    __shared__ __align__(16) float gS[G4];

    float w[HH];
#pragma unroll
    for (int k = 0; k < HH; k += 4) {
        const float4 v = *reinterpret_cast<const float4*>(Whh + tid * HH + k);
        w[k] = v.x; w[k + 1] = v.y; w[k + 2] = v.z; w[k + 3] = v.w;
    }
    const int a4  = (tid >> 6) << 2;   // proj row base (0,4,...,28)
    const int jg8 = (tid & 63) << 3;   // proj col base (0,8,...,504)
    float bias8[8];
#pragma unroll
    for (int c = 0; c < 8; ++c) bias8[c] = bih[jg8 + c] + bhh[jg8 + c];
    float fw0 = 0.f, fw1 = 0.f, fcbv = 0.f;
    if (tid < 64) { fw0 = fcw[tid]; fw1 = fcw[tid + 64]; fcbv = fcb[0]; }
    if (tid < HH) { hS[tid] = 0.0f; cS[tid] = 0.0f; }
    __syncthreads();

    const float* hb = h0in + (size_t)b * TT * HH;
    float* ob = out + (size_t)b * TT;

    for (int t0 = 0; t0 < TT; t0 += 32) {
        // ---- stage h0[b, t0:t0+32, :] into LDS (4096 floats) ----
        {
            const float4* src = reinterpret_cast<const float4*>(hb + t0 * HH);
            float4* dst = reinterpret_cast<float4*>(&h0S[0][0]);
            dst[tid]       = src[tid];
            dst[tid + 512] = src[tid + 512];
        }
        __syncthreads();

        // ---- input projection: acc[r][c] = bias + sum_k h0S[a4+r][k]*WT[k][jg8+c]
        float acc[4][8];
#pragma unroll
        for (int r = 0; r < 4; ++r)
#pragma unroll
            for (int c = 0; c < 8; ++c) acc[r][c] = bias8[c] * 0.25f; // split bias over 4 rows? no:
        // (re-init properly: bias added once per output element)
#pragma unroll
        for (int r = 0; r < 4; ++r)
#pragma unroll
            for (int c = 0; c < 8; ++c) acc[r][c] = bias8[c];

        for (int k4 = 0; k4 < HH; k4 += 4) {
            const float* wp = WT + (size_t)k4 * G4 + jg8;
            const float4 w0a = *reinterpret_cast<const float4*>(wp);
            const float4 w0b = *reinterpret_cast<const float4*>(wp + 4);
            const float4 w1a = *reinterpret_cast<const float4*>(wp + G4);
            const float4 w1b = *reinterpret_cast<const float4*>(wp + G4 + 4);
            const float4 w2a = *reinterpret_cast<const float4*>(wp + 2 * G4);
            const float4 w2b = *reinterpret_cast<const float4*>(wp + 2 * G4 + 4);
            const float4 w3a = *reinterpret_cast<const float4*>(wp + 3 * G4);
            const float4 w3b = *reinterpret_cast<const float4*>(wp + 3 * G4 + 4);
#pragma unroll
            for (int r = 0; r < 4; ++r) {
                const float4 hv = *reinterpret_cast<const float4*>(&h0S[a4 + r][k4]);
#define FMA8(hh, va, vb)                                                       \
    acc[r][0] = fmaf(hh, va.x, acc[r][0]); acc[r][1] = fmaf(hh, va.y, acc[r][1]); \
    acc[r][2] = fmaf(hh, va.z, acc[r][2]); acc[r][3] = fmaf(hh, va.w, acc[r][3]); \
    acc[r][4] = fmaf(hh, vb.x, acc[r][4]); acc[r][5] = fmaf(hh, vb.y, acc[r][5]); \
    acc[r][6] = fmaf(hh, vb.z, acc[r][6]); acc[r][7] = fmaf(hh, vb.w, acc[r][7]);
                FMA8(hv.x, w0a, w0b)
                FMA8(hv.y, w1a, w1b)
                FMA8(hv.z, w2a, w2b)
                FMA8(hv.w, w3a, w3b)
#undef FMA8
            }
        }
#pragma unroll
        for (int r = 0; r < 4; ++r)
#pragma unroll
            for (int c = 0; c < 8; ++c)
                xgS[a4 + r][jg8 + c] = acc[r][c];
        __syncthreads();

        // ---- 32 sequential recurrent steps ----
        for (int i = 0; i < 32; ++i) {
            float a0 = xgS[i][tid], a1 = 0.f, a2 = 0.f, a3 = 0.f;
#pragma unroll
            for (int k = 0; k < HH; k += 4) {
                const float4 hv = *reinterpret_cast<const float4*>(hS + k);  // broadcast
                a0 = fmaf(hv.x, w[k],     a0);
                a1 = fmaf(hv.y, w[k + 1], a1);
                a2 = fmaf(hv.z, w[k + 2], a2);
                a3 = fmaf(hv.w, w[k + 3], a3);
            }
            gS[tid] = (a0 + a1) + (a2 + a3);
            __syncthreads();
            if (tid < HH) {
                const float gi = sigm(gS[tid]);
                const float gf = sigm(gS[tid + HH]);
                const float gg = tanh_f(gS[tid + 2 * HH]);
                const float go = sigm(gS[tid + 3 * HH]);
                const float c = gf * cS[tid] + gi * gg;
                const float h = go * tanh_f(c);
                cS[tid] = c; hS[tid] = h;
            }
            __syncthreads();
            if (tid < 64) {  // FC head, wave 0 only; reads hS written above
                float p = fmaf(fw0, hS[tid], fw1 * hS[tid + 64]);
#pragma unroll
                for (int s = 32; s > 0; s >>= 1) p += __shfl_xor(p, s, 64);
                if (tid == 0) ob[t0 + i] = p + fcbv;
            }
        }
        __syncthreads();  // protect h0S/xgS before next chunk's staging
    }
}

extern "C" void kernel_launch(void* const* d_in, const int* in_sizes, int n_in,
                              void* d_out, int out_size, void* d_ws, size_t ws_size,
                              hipStream_t stream)
{
    const float* x    = (const float*)d_in[0];
    const float* Wih0 = (const float*)d_in[1];
    const float* Whh0 = (const float*)d_in[2];
    const float* bih0 = (const float*)d_in[3];
    const float* bhh0 = (const float*)d_in[4];
    const float* Wih1 = (const float*)d_in[5];
    const float* Whh1 = (const float*)d_in[6];
    const float* bih1 = (const float*)d_in[7];
    const float* bhh1 = (const float*)d_in[8];
    const float* fcw  = (const float*)d_in[9];
    const float* fcb  = (const float*)d_in[10];
    float* out = (float*)d_out;

    float* h0 = (float*)d_ws;                            // 256*1024*128 fp32 = 128 MiB
    float* WT = h0 + (size_t)256 * TT * HH;              // 128*512 fp32 = 256 KiB

    transp<<<256, 256, 0, stream>>>(Wih1, WT);
    lstm0<<<256, 512, 0, stream>>>(x, Wih0, Whh0, bih0, bhh0, h0);
    lstm1<<<256, 512, 0, stream>>>(h0, WT, Whh1, bih1, bhh1, fcw, fcb, out);
}

// Round 2
// 2187.984 us; speedup vs baseline: 1.4717x; 1.4717x over previous
//
#include <hip/hip_runtime.h>

#define TT 1024
#define HH 128
#define G4 512

__device__ __forceinline__ float sigm(float x) {
    return __builtin_amdgcn_rcpf(1.0f + __expf(-x));
}
__device__ __forceinline__ float tanh_f(float x) {
    return 1.0f - 2.0f * __builtin_amdgcn_rcpf(1.0f + __expf(2.0f * x));
}

// ============================ layer 0 =======================================
// 256 blocks (one batch row), 1024 threads = 16 waves (4/SIMD).
// Thread t: slice = t>>8 (k-quarter), gate pair g0 = (t&255)*2.
// Holds Whh rows [g0,g0+1] x k-slice (64 fp32 in VGPRs).
// Step: W(all): partial dots -> pS | R(512): reduce+bias+x-term+activation
//       | F(128): c,h update (c in reg), write hS + h0out.
__global__ __launch_bounds__(1024) void lstm0(
    const float* __restrict__ x, const float* __restrict__ Wih,
    const float* __restrict__ Whh, const float* __restrict__ bih,
    const float* __restrict__ bhh, float* __restrict__ h0out)
{
    const int b   = blockIdx.x;
    const int tid = threadIdx.x;
    const int slice = tid >> 8;          // 0..3
    const int g0    = (tid & 255) * 2;   // 0,2,...,510
    const int k0    = slice * 32;

    __shared__ __align__(16) float xS[TT];        // 4 KB
    __shared__ __align__(16) float pS[4][G4];     // 8 KB
    __shared__ __align__(16) float actS[G4];      // 2 KB
    __shared__ __align__(16) float hS[HH];

    float w0[32], w1[32];
#pragma unroll
    for (int k = 0; k < 32; k += 4) {
        const float4 v0 = *reinterpret_cast<const float4*>(Whh + (size_t)g0 * HH + k0 + k);
        w0[k] = v0.x; w0[k+1] = v0.y; w0[k+2] = v0.z; w0[k+3] = v0.w;
        const float4 v1 = *reinterpret_cast<const float4*>(Whh + (size_t)(g0 + 1) * HH + k0 + k);
        w1[k] = v1.x; w1[k+1] = v1.y; w1[k+2] = v1.z; w1[k+3] = v1.w;
    }

    float bias_r = 0.f, wih_r = 0.f;
    if (tid < G4) { bias_r = bih[tid] + bhh[tid]; wih_r = Wih[tid]; }
    float c_reg = 0.f;
    if (tid < HH) hS[tid] = 0.f;
    xS[tid] = x[(size_t)b * TT + tid];
    __syncthreads();

    float* hb = h0out + (size_t)b * TT * HH;

    for (int t = 0; t < TT; ++t) {
        // ---- W: partial dot products (all 1024 threads) ----
        float a00 = 0.f, a01 = 0.f, a10 = 0.f, a11 = 0.f;
#pragma unroll
        for (int k = 0; k < 32; k += 4) {
            const float4 hv = *reinterpret_cast<const float4*>(hS + k0 + k); // broadcast
            a00 = fmaf(hv.x, w0[k],   a00);  a01 = fmaf(hv.y, w0[k+1], a01);
            a00 = fmaf(hv.z, w0[k+2], a00);  a01 = fmaf(hv.w, w0[k+3], a01);
            a10 = fmaf(hv.x, w1[k],   a10);  a11 = fmaf(hv.y, w1[k+1], a11);
            a10 = fmaf(hv.z, w1[k+2], a10);  a11 = fmaf(hv.w, w1[k+3], a11);
        }
        float2 pp; pp.x = a00 + a01; pp.y = a10 + a11;
        *reinterpret_cast<float2*>(&pS[slice][g0]) = pp;
        __syncthreads();

        // ---- R: reduce slices + input term + activation (512 threads) ----
        if (tid < G4) {
            float g = (pS[0][tid] + pS[1][tid]) + (pS[2][tid] + pS[3][tid]);
            g += fmaf(xS[t], wih_r, bias_r);
            actS[tid] = ((tid >> 7) == 2) ? tanh_f(g) : sigm(g);
        }
        __syncthreads();

        // ---- F: cell/hidden update (128 threads) ----
        if (tid < HH) {
            const float gi = actS[tid];
            const float gf = actS[tid + 128];
            const float gg = actS[tid + 256];
            const float go = actS[tid + 384];
            c_reg = fmaf(gf, c_reg, gi * gg);
            const float h = go * tanh_f(c_reg);
            hS[tid] = h;
            hb[(size_t)t * HH + tid] = h;
        }
        __syncthreads();
    }
}

// ---------------- W_ih1 transpose: [512,128] -> [128,512] -------------------
__global__ void transp(const float* __restrict__ Wih1, float* __restrict__ WT)
{
    const int i = blockIdx.x * 256 + threadIdx.x;  // 0..65535
    const int j = i & (G4 - 1);
    const int k = i >> 9;
    WT[k * G4 + j] = Wih1[j * HH + k];
}

// ============================ layer 1 + FC ==================================
// Same recurrent structure as lstm0. Per 32-step chunk: stage h0 chunk to LDS,
// input projection (thread = 8 rows x 2 cols, WT streamed as float2 from L2,
// h0 rows broadcast from LDS), then 32 recurrent steps; FC head fused in F.
__global__ __launch_bounds__(1024) void lstm1(
    const float* __restrict__ h0in, const float* __restrict__ WT,
    const float* __restrict__ Whh, const float* __restrict__ bih,
    const float* __restrict__ bhh, const float* __restrict__ fcw,
    const float* __restrict__ fcb, float* __restrict__ out)
{
    const int b   = blockIdx.x;
    const int tid = threadIdx.x;
    const int slice = tid >> 8;
    const int g0    = (tid & 255) * 2;
    const int k0    = slice * 32;

    __shared__ __align__(16) float h0S[32][HH];   // 16 KB
    __shared__ __align__(16) float xgS[32][G4];   // 64 KB
    __shared__ __align__(16) float pS[4][G4];     // 8 KB
    __shared__ __align__(16) float actS[G4];      // 2 KB
    __shared__ __align__(16) float hS[HH];
    __shared__ float fcS[2];

    float w0[32], w1[32];
#pragma unroll
    for (int k = 0; k < 32; k += 4) {
        const float4 v0 = *reinterpret_cast<const float4*>(Whh + (size_t)g0 * HH + k0 + k);
        w0[k] = v0.x; w0[k+1] = v0.y; w0[k+2] = v0.z; w0[k+3] = v0.w;
        const float4 v1 = *reinterpret_cast<const float4*>(Whh + (size_t)(g0 + 1) * HH + k0 + k);
        w1[k] = v1.x; w1[k+1] = v1.y; w1[k+2] = v1.z; w1[k+3] = v1.w;
    }

    float bias_r = 0.f;
    if (tid < G4) bias_r = bih[tid] + bhh[tid];
    float fcw_r = 0.f, fcbv = 0.f;
    if (tid < HH) fcw_r = fcw[tid];
    fcbv = fcb[0];
    float c_reg = 0.f;
    if (tid < HH) hS[tid] = 0.f;

    // proj tiling: 256 col-groups x 4 row-groups
    const int c0 = (tid & 255) * 2;    // col pair
    const int r0 = (tid >> 8) * 8;     // 8 rows

    const float* hb = h0in + (size_t)b * TT * HH;
    float* ob = out + (size_t)b * TT;
    __syncthreads();

    for (int t0 = 0; t0 < TT; t0 += 32) {
        // ---- stage h0[b, t0:t0+32, :] (4096 floats, 1 float4/thread) ----
        reinterpret_cast<float4*>(&h0S[0][0])[tid] =
            reinterpret_cast<const float4*>(hb + (size_t)t0 * HH)[tid];
        __syncthreads();

        // ---- input projection into xgS ----
        {
            float2 acc[8];
#pragma unroll
            for (int r = 0; r < 8; ++r) { acc[r].x = 0.f; acc[r].y = 0.f; }
            for (int k = 0; k < HH; k += 4) {
                const float* wp = WT + (size_t)k * G4 + c0;
                const float2 wv0 = *reinterpret_cast<const float2*>(wp);
                const float2 wv1 = *reinterpret_cast<const float2*>(wp + G4);
                const float2 wv2 = *reinterpret_cast<const float2*>(wp + 2 * G4);
                const float2 wv3 = *reinterpret_cast<const float2*>(wp + 3 * G4);
#pragma unroll
                for (int r = 0; r < 8; ++r) {
                    const float4 hv = *reinterpret_cast<const float4*>(&h0S[r0 + r][k]); // broadcast
                    acc[r].x = fmaf(hv.x, wv0.x, acc[r].x); acc[r].y = fmaf(hv.x, wv0.y, acc[r].y);
                    acc[r].x = fmaf(hv.y, wv1.x, acc[r].x); acc[r].y = fmaf(hv.y, wv1.y, acc[r].y);
                    acc[r].x = fmaf(hv.z, wv2.x, acc[r].x); acc[r].y = fmaf(hv.z, wv2.y, acc[r].y);
                    acc[r].x = fmaf(hv.w, wv3.x, acc[r].x); acc[r].y = fmaf(hv.w, wv3.y, acc[r].y);
                }
            }
#pragma unroll
            for (int r = 0; r < 8; ++r)
                *reinterpret_cast<float2*>(&xgS[r0 + r][c0]) = acc[r];
        }
        __syncthreads();

        // ---- 32 recurrent steps ----
        for (int i = 0; i < 32; ++i) {
            float a00 = 0.f, a01 = 0.f, a10 = 0.f, a11 = 0.f;
#pragma unroll
            for (int k = 0; k < 32; k += 4) {
                const float4 hv = *reinterpret_cast<const float4*>(hS + k0 + k); // broadcast
                a00 = fmaf(hv.x, w0[k],   a00);  a01 = fmaf(hv.y, w0[k+1], a01);
                a00 = fmaf(hv.z, w0[k+2], a00);  a01 = fmaf(hv.w, w0[k+3], a01);
                a10 = fmaf(hv.x, w1[k],   a10);  a11 = fmaf(hv.y, w1[k+1], a11);
                a10 = fmaf(hv.z, w1[k+2], a10);  a11 = fmaf(hv.w, w1[k+3], a11);
            }
            float2 pp; pp.x = a00 + a01; pp.y = a10 + a11;
            *reinterpret_cast<float2*>(&pS[slice][g0]) = pp;
            __syncthreads();

            if (tid < G4) {
                float g = (pS[0][tid] + pS[1][tid]) + (pS[2][tid] + pS[3][tid]);
                g += xgS[i][tid] + bias_r;
                actS[tid] = ((tid >> 7) == 2) ? tanh_f(g) : sigm(g);
            }
            __syncthreads();

            if (tid < HH) {
                const float gi = actS[tid];
                const float gf = actS[tid + 128];
                const float gg = actS[tid + 256];
                const float go = actS[tid + 384];
                c_reg = fmaf(gf, c_reg, gi * gg);
                const float h = go * tanh_f(c_reg);
                hS[tid] = h;
                float p = fcw_r * h;
#pragma unroll
                for (int s = 32; s; s >>= 1) p += __shfl_xor(p, s, 64);
                if ((tid & 63) == 0) fcS[tid >> 6] = p;
            }
            __syncthreads();
            if (tid == 0) ob[t0 + i] = fcS[0] + fcS[1] + fcbv;
        }
    }
}

extern "C" void kernel_launch(void* const* d_in, const int* in_sizes, int n_in,
                              void* d_out, int out_size, void* d_ws, size_t ws_size,
                              hipStream_t stream)
{
    const float* x    = (const float*)d_in[0];
    const float* Wih0 = (const float*)d_in[1];
    const float* Whh0 = (const float*)d_in[2];
    const float* bih0 = (const float*)d_in[3];
    const float* bhh0 = (const float*)d_in[4];
    const float* Wih1 = (const float*)d_in[5];
    const float* Whh1 = (const float*)d_in[6];
    const float* bih1 = (const float*)d_in[7];
    const float* bhh1 = (const float*)d_in[8];
    const float* fcw  = (const float*)d_in[9];
    const float* fcb  = (const float*)d_in[10];
    float* out = (float*)d_out;

    float* h0 = (float*)d_ws;                            // 128 MiB
    float* WT = h0 + (size_t)256 * TT * HH;              // 256 KiB

    transp<<<256, 256, 0, stream>>>(Wih1, WT);
    lstm0<<<256, 1024, 0, stream>>>(x, Wih0, Whh0, bih0, bhh0, h0);
    lstm1<<<256, 1024, 0, stream>>>(h0, WT, Whh1, bih1, bhh1, fcw, fcb, out);
}